// Round 6
// baseline (340.679 us; speedup 1.0000x reference)
//
#include <hip/hip_runtime.h>

// [T+1, B] = [1024, 4096] fp32, time-major.
#define T      1023
#define B      4096
#define CHUNK  16
#define NCHUNK 64        // 64 chunks of 16 steps; t=1023 is an identity pad step
#define NCB    8         // col-blocks of 512 columns
#define NBLK   (NCHUNK * NCB)   // 512 blocks = 256 CUs x 2 blocks/CU (LDS-limited)
                                // -> ALL blocks co-resident: spin cannot deadlock

#define GAMMA     0.99f
#define TD_LAMBDA 0.95f

__global__ void k_zero(int* __restrict__ flags) { flags[threadIdx.x] = 0; }

// GAE: adv[t] = nl_t*(delta_t + wd_t*adv[t+1]) == a_t + b_t*adv[t+1]
// loss[t] = (adv[t] + tv[t] - value[t])^2
__global__ __launch_bounds__(512, 4) void k_gae(
    const float* __restrict__ value, const float* __restrict__ tv,
    const float* __restrict__ rew, const int* __restrict__ st,
    const float* __restrict__ disc,
    float* __restrict__ AggA, float* __restrict__ AggB,
    int* __restrict__ flags, float* __restrict__ out)
{
    __shared__ float sa[CHUNK * 512];   // 32 KB
    __shared__ float sb[CHUNK * 512];   // 32 KB  (64 KB total -> 2 blocks/CU)

    const int bid = blockIdx.x;
    const int cb  = bid & (NCB - 1);
    const int c   = (NCHUNK - 1) - (bid >> 3);   // high chunks dispatch first
    const int col = cb * 512 + threadIdx.x;
    const int s   = c * CHUNK;

    // ---- Phase 1: compose own chunk; per-step (a,b) -> LDS (not registers) ----
    float A = 0.f, Bf = 1.f;
    float tvn = tv[min(s + CHUNK, T) * B + col];
    #pragma unroll
    for (int k = CHUNK - 1; k >= 0; --k) {
        const int t = s + k;
        float a = 0.f, b = 1.f;                   // identity pad (t == 1023 only)
        if (t < T) {
            const int i0 = t * B + col;
            const int i1 = i0 + B;
            const float d1    = disc[i1] * GAMMA;
            const float tvt   = tv[i0];
            const float delta = rew[i1] + d1 * tvn - tvt;
            const float nl    = (st[i0] == 2) ? 0.f : 1.f;
            a = nl * delta;
            b = nl * (d1 * TD_LAMBDA);
            tvn = tvt;
        }
        sa[k * 512 + threadIdx.x] = a;            // lane-stride 1: conflict-free
        sb[k * 512 + threadIdx.x] = b;
        A  = fmaf(b, A, a);
        Bf *= b;
    }

    // ---- Phase 2: publish aggregate, release flag ----
    AggA[c * B + col] = A;
    AggB[c * B + col] = Bf;
    __threadfence();
    __syncthreads();                              // all threads' stores fenced
    if (threadIdx.x == 0)
        __hip_atomic_store(&flags[c * NCB + cb], 1,
                           __ATOMIC_RELEASE, __HIP_MEMORY_SCOPE_AGENT);

    // ---- Phase 3: lookback fold over chunks c+1..63 (forward, batched by 8) ----
    // Maintain affine (P,Q): adv_right(c) = P + Q * x with x = 0 at the end.
    float P = 0.f, Q = 1.f;
    for (int base = c + 1; base < NCHUNK; base += 8) {
        const int nb = min(8, NCHUNK - base);
        if (threadIdx.x < nb) {                   // 8 threads spin, 1 flag each
            const int f = (base + threadIdx.x) * NCB + cb;
            while (!__hip_atomic_load(&flags[f], __ATOMIC_RELAXED,
                                      __HIP_MEMORY_SCOPE_AGENT))
                __builtin_amdgcn_s_sleep(8);
        }
        __syncthreads();
        __builtin_amdgcn_fence(__ATOMIC_ACQUIRE, "agent");
        #pragma unroll
        for (int k = 0; k < 8; ++k) {
            if (k < nb) {
                const int i = (base + k) * B + col;
                const float Ak = AggA[i];
                const float Bk = AggB[i];
                P = fmaf(Q, Ak, P);
                Q *= Bk;
            }
        }
    }
    float adv = P;                                // adv entering chunk c

    // ---- Phase 4: replay from LDS; emit loss ----
    if (c == NCHUNK - 1)
        out[T * B + col] = 0.f;                   // tensor_extend_zero row
    #pragma unroll
    for (int k = CHUNK - 1; k >= 0; --k) {
        adv = fmaf(sb[k * 512 + threadIdx.x], adv, sa[k * 512 + threadIdx.x]);
        const int t = s + k;
        if (t < T) {
            const int i0 = t * B + col;
            const float td = adv + tv[i0] - value[i0];   // tv L2-warm, value cold
            out[i0] = td * td;
        }
    }
}

extern "C" void kernel_launch(void* const* d_in, const int* in_sizes, int n_in,
                              void* d_out, int out_size, void* d_ws, size_t ws_size,
                              hipStream_t stream) {
    // setup_inputs order: value, target_value, reward, step_type, discount
    const float* value = (const float*)d_in[0];
    const float* tv    = (const float*)d_in[1];
    const float* rew   = (const float*)d_in[2];
    const int*   st    = (const int*)d_in[3];
    const float* disc  = (const float*)d_in[4];
    float* out = (float*)d_out;

    float* AggA  = (float*)d_ws;                       // [NCHUNK][B] — 1 MiB
    float* AggB  = AggA + (size_t)NCHUNK * B;          // 1 MiB
    int*   flags = (int*)(AggB + (size_t)NCHUNK * B);  // 512 ints

    k_zero<<<1, NBLK, 0, stream>>>(flags);
    k_gae<<<NBLK, 512, 0, stream>>>(value, tv, rew, st, disc,
                                    AggA, AggB, flags, out);
}